// Round 4
// baseline (1460.840 us; speedup 1.0000x reference)
//
#include <hip/hip_runtime.h>

#define NT 512

typedef __attribute__((ext_vector_type(8)))  short bh8;   // 8 bf16
typedef __attribute__((ext_vector_type(16))) float f16v;  // 32x32 acc
typedef __attribute__((ext_vector_type(4)))  float f4v;   // 16x16 acc

// ---- d_ws layout (ushort units): pre-swizzled 64-lane x 16B fragment dumps.
// Every frag is 512 ush (1KB); a wave loads it as base + lane*8 (fully coalesced).
#define FW_H    0      // sconv expanded-weight B-frags, 56 frags (28672)
#define FW_L    28672
#define W2A32_H 57344  // stage2 32x32 A-frags (isft), 9 frags (4608)
#define W2A32_L 61952
#define W3B_H   66560  // stage3 B-frags (scale*sft), 9 frags (4608)
#define W3B_L   71168  // end 75776 ush = 151552 B

// ---- LDS layout (ushort units): activations only ----
#define SHo  0      // s planes [o][p] stride 104 (6656); overlay: y planes [o][k] stride 72
#define SLo  6656
#define XHo  13312  // x planes [k][c] stride 72 (3456)
#define XLo  16768
#define ZOFF 20224  // 8-ush zero block for OOB sconv A-frag reads
#define NU   20232  // 40464 B -> 4 blocks/CU (with 512 thr: 32 waves/CU)

__device__ __forceinline__ unsigned short f2bf(float f) {  // RNE
  unsigned u = __float_as_uint(f);
  return (unsigned short)((u + 0x7fffu + ((u >> 16) & 1u)) >> 16);
}
__device__ __forceinline__ float bf2f(unsigned short h) {
  return __uint_as_float(((unsigned)h) << 16);
}
__device__ __forceinline__ int lidxf(int k) {  // degree band l/2 for coeff k
  return (k < 1) ? 0 : (k < 6) ? 1 : (k < 15) ? 2 : (k < 28) ? 3 : 4;
}
__device__ __forceinline__ float scale_from_j(int j) {  // sqrt(pi/(4j+1))
  float s = 1.7724539f;
  s = (j == 1) ? 0.79266548f : s;
  s = (j == 2) ? 0.59081795f : s;
  s = (j == 3) ? 0.49159026f : s;
  s = (j >= 4) ? 0.42988324f : s;
  return s;
}
__device__ __forceinline__ float rcp_from_j(int j) {  // 1/scale
  float s = 0.56418958f;
  s = (j == 1) ? 1.2615663f : s;
  s = (j == 2) ? 1.6925688f : s;
  s = (j == 3) ? 2.0342144f : s;
  s = (j >= 4) ? 2.3262120f : s;
  return s;
}
// packed split: hi = trunc-bf16 pair via v_perm; lo = trunc(v - bf2f(hi)) pair
__device__ __forceinline__ unsigned pk_hi(float a, float b) {
  return __builtin_amdgcn_perm(__float_as_uint(b), __float_as_uint(a), 0x07060302u);
}
__device__ __forceinline__ void split_store4(unsigned short* dh, unsigned short* dl,
                                             float v0, float v1, float v2, float v3) {
  const unsigned u0 = __float_as_uint(v0), u1 = __float_as_uint(v1);
  const unsigned u2 = __float_as_uint(v2), u3 = __float_as_uint(v3);
  const float d0 = v0 - __uint_as_float(u0 & 0xffff0000u);
  const float d1 = v1 - __uint_as_float(u1 & 0xffff0000u);
  const float d2 = v2 - __uint_as_float(u2 & 0xffff0000u);
  const float d3 = v3 - __uint_as_float(u3 & 0xffff0000u);
  *(uint2*)dh = make_uint2(pk_hi(v0, v1), pk_hi(v2, v3));
  *(uint2*)dl = make_uint2(pk_hi(d0, d1), pk_hi(d2, d3));
}

// ======================= pre-kernel: build fragment dumps =======================
__global__ void scnn_prep(const float* __restrict__ sft, const float* __restrict__ isft,
                          const float* __restrict__ w1, const float* __restrict__ w2,
                          const float* __restrict__ w3, const float* __restrict__ w4,
                          const float* __restrict__ w5, const float* __restrict__ w6,
                          unsigned short* __restrict__ wsu) {
  const int gid = blockIdx.x * NT + threadIdx.x;
  const int gstr = gridDim.x * NT;
  const float* wp[6] = {w1, w2, w3, w4, w5, w6};
  const int CIN[6] = {4, 16, 32, 64, 32, 16};
  const int COUT[6] = {16, 32, 64, 32, 16, 4};
  const int LG[6] = {3, 4, 5, 6, 5, 4};
  const int NST[6] = {2, 3, 5, 10, 5, 3};
  const int NTC[6] = {1, 2, 4, 2, 1, 1};
  const int FOFF[6] = {0, 2, 8, 28, 48, 53};
#pragma unroll
  for (int l = 0; l < 6; ++l) {
    const int cin = CIN[l], cout = COUT[l], lg = LG[l], cinP = 1 << lg;
    const int nst = NST[l];
    const int n = NTC[l] * nst * 512;
    const float* w = wp[l];
    const int base = FOFF[l] * 512;
    for (int i = gid; i < n; i += gstr) {
      const int fid = i >> 9, lane = (i >> 3) & 63, e = i & 7;
      const int nt = fid / nst, st = fid - nt * nst;
      const int o = nt * 16 + (lane & 15);
      const int s = st * 32 + (lane >> 4) * 8 + e;
      const int j = s >> lg, c = s & (cinP - 1);
      float v = 0.f;
      if (o < cout && j < 5 && c < cin) v = w[(o * cin + c) * 5 + j];
      const unsigned short h = f2bf(v);
      wsu[FW_H + base + i] = h;
      wsu[FW_L + base + i] = f2bf(v - bf2f(h));
    }
  }
  for (int i = gid; i < 9 * 512; i += gstr) {  // stage2 32x32 A-frags (isft)
    const int fid = i >> 9, lane = (i >> 3) & 63, e = i & 7;
    const int mt = fid / 3, ks = fid - mt * 3;
    const int p = mt * 32 + (lane & 31);
    const int k = ks * 16 + (lane >> 5) * 8 + e;
    const float v = (p < 90 && k < 45) ? isft[p * 45 + k] : 0.f;
    const unsigned short h = f2bf(v);
    wsu[W2A32_H + i] = h;
    wsu[W2A32_L + i] = f2bf(v - bf2f(h));
  }
  for (int i = gid; i < 9 * 512; i += gstr) {  // stage3 B-frags (scale*sft)
    const int fid = i >> 9, lane = (i >> 3) & 63, e = i & 7;
    const int ntK = fid / 3, sl = fid - ntK * 3;
    const int kk = ntK * 16 + (lane & 15);
    const int p = sl * 32 + (lane >> 4) * 8 + e;
    float v = 0.f;
    if (kk < 45 && p < 90) v = sft[kk * 90 + p] * scale_from_j(lidxf(kk));
    const unsigned short h = f2bf(v);
    wsu[W3B_H + i] = h;
    wsu[W3B_L + i] = f2bf(v - bf2f(h));
  }
}

// stage2 partial: accumulate one mt (p-tile) into acc given shared y operands.
template <int MT>
__device__ __forceinline__ void s2accum(f16v& a, const unsigned short* __restrict__ wsu,
                                        int ks, int lof, bh8 bhv, bh8 blv) {
  const unsigned short* fh = wsu + W2A32_H + (MT * 3 + ks) * 512 + lof;
  const bh8 ah = *(const bh8*)&fh[0];
  const bh8 al = *(const bh8*)&fh[W2A32_L - W2A32_H];
  a = __builtin_amdgcn_mfma_f32_32x32x16_bf16(ah, bhv, a, 0, 0, 0);
  a = __builtin_amdgcn_mfma_f32_32x32x16_bf16(al, bhv, a, 0, 0, 0);
  a = __builtin_amdgcn_mfma_f32_32x32x16_bf16(ah, blv, a, 0, 0, 0);
}
__device__ __forceinline__ void writes_s(unsigned short* U, f16v acc, int mt,
                                         int nt, int llo, int lhi) {
  const int o = nt * 32 + llo;
#pragma unroll
  for (int g = 0; g < 4; ++g) {
    const int p0 = mt * 32 + g * 8 + lhi * 4;
    split_store4(&U[SHo + o * 104 + p0], &U[SLo + o * 104 + p0],
                 fmaxf(acc[g * 4 + 0], 0.f), fmaxf(acc[g * 4 + 1], 0.f),
                 fmaxf(acc[g * 4 + 2], 0.f), fmaxf(acc[g * 4 + 3], 0.f));
  }
}

// stage3 partial: accumulate one ntK (k'-tile) into acc given shared s operands.
template <int NTK>
__device__ __forceinline__ void d3accum(f4v& a, const unsigned short* __restrict__ wsu,
                                        int sl, int lof, bh8 ah, bh8 al) {
  const unsigned short* fb = wsu + W3B_H + (NTK * 3 + sl) * 512 + lof;
  const bh8 bhv = *(const bh8*)&fb[0];
  const bh8 blv = *(const bh8*)&fb[W3B_L - W3B_H];
  a = __builtin_amdgcn_mfma_f32_16x16x32_bf16(ah, bhv, a, 0, 0, 0);
  a = __builtin_amdgcn_mfma_f32_16x16x32_bf16(al, bhv, a, 0, 0, 0);
  a = __builtin_amdgcn_mfma_f32_16x16x32_bf16(ah, blv, a, 0, 0, 0);
}

// ---- stage (a): one wave per mt, ALL nt tiles accumulated together so the
// X-operand LDS reads happen once per (mt,st) instead of once per tile.
template <int layer, int mt>
__device__ __forceinline__ void atile_multi(unsigned short* U,
                                            const unsigned short* __restrict__ wsu,
                                            int l15, int q4, int lof) {
  constexpr int lg   = (layer == 0) ? 3 : (layer == 1) ? 4 : (layer == 2) ? 5
                     : (layer == 3) ? 6 : (layer == 4) ? 5 : 4;
  constexpr int cinP = 1 << lg;
  constexpr int NSTc = (layer == 0) ? 2 : (layer == 1) ? 3 : (layer == 2) ? 5
                     : (layer == 3) ? 10 : (layer == 4) ? 5 : 3;
  constexpr int FOFFc= (layer == 0) ? 0 : (layer == 1) ? 2 : (layer == 2) ? 8
                     : (layer == 3) ? 28 : (layer == 4) ? 48 : 53;
  constexpr int nt16 = (layer == 2) ? 4 : (layer == 1 || layer == 3) ? 2 : 1;
  constexpr int hi5 = (5 * cinP + 31) >> 5;
  constexpr int hi4 = (4 * cinP + 31) >> 5;
  constexpr int lo3 = (3 * cinP) >> 5;
  constexpr int lo4 = cinP >> 3;
  constexpr int lo = (mt == 0) ? 0 : (mt == 1) ? lo3 : lo4;
  constexpr int hi = (mt == 0) ? hi4 : hi5;

  const int k = mt * 16 + l15;
  const int jb = lidxf(k) << lg;
  f4v acc[nt16];
#pragma unroll
  for (int n = 0; n < nt16; ++n) { acc[n][0] = acc[n][1] = acc[n][2] = acc[n][3] = 0.f; }
#pragma unroll
  for (int st = lo; st < hi; ++st) {
    const int S = st * 32 + q4 * 8;
    const unsigned c0 = (unsigned)(S - jb);
    const int base = XHo + k * 72 + (int)(c0 & 56u);
    const bool oob = c0 >= (unsigned)cinP;
    const int axh = oob ? ZOFF : base;
    const int axl = oob ? ZOFF : (base + (XLo - XHo));
    const bh8 xh = *(const bh8*)&U[axh];
    const bh8 xl = *(const bh8*)&U[axl];
#pragma unroll
    for (int n = 0; n < nt16; ++n) {
      const unsigned short* wf = wsu + FW_H + (FOFFc + n * NSTc + st) * 512 + lof;
      const bh8 wh = *(const bh8*)&wf[0];
      const bh8 wl = *(const bh8*)&wf[FW_L - FW_H];
      acc[n] = __builtin_amdgcn_mfma_f32_16x16x32_bf16(xh, wh, acc[n], 0, 0, 0);
      acc[n] = __builtin_amdgcn_mfma_f32_16x16x32_bf16(xl, wh, acc[n], 0, 0, 0);
      acc[n] = __builtin_amdgcn_mfma_f32_16x16x32_bf16(xh, wl, acc[n], 0, 0, 0);
    }
  }
  const int kq = mt * 16 + q4 * 4;
#pragma unroll
  for (int n = 0; n < nt16; ++n) {
    const int o = n * 16 + l15;
    split_store4(&U[SHo + o * 72 + kq], &U[SLo + o * 72 + kq],
                 acc[n][0], acc[n][1], acc[n][2], acc[n][3]);
  }
}

// ======================= per-layer body (compile-time specialized) =======
template <int layer>
__device__ __forceinline__ void layer_body(unsigned short* U,
                                           const unsigned short* __restrict__ wsu,
                                           int tid, int wv, int llo, int lhi,
                                           int l15, int q4, int lof) {
  constexpr int nt16 = (layer == 2) ? 4 : (layer == 1 || layer == 3) ? 2 : 1;
  constexpr int n32  = (layer == 2) ? 2 : 1;

  // ---- (a) sconv via MFMA: wave mt owns all nt accumulators (shared X reads)
  if (wv == 0)      atile_multi<layer, 0>(U, wsu, l15, q4, lof);
  else if (wv == 1) atile_multi<layer, 1>(U, wsu, l15, q4, lof);
  else if (wv == 2) atile_multi<layer, 2>(U, wsu, l15, q4, lof);
  __syncthreads();

  // ---- (b)+(c) stage2 MFMA, shared y reads: per nt-group g, wave r=0 does
  //      mt{0,1} (2 accs), wave r=1 does mt{2}. Accs live across the barrier.
  {
    const int g = wv >> 1, r = wv & 1;
    const bool act = g < n32;
    f16v acc0, acc1;
    if (act) {
      if (r == 0) {
#pragma unroll
        for (int e = 0; e < 16; ++e) { acc0[e] = 0.f; acc1[e] = 0.f; }
#pragma unroll
        for (int ks = 0; ks < 3; ++ks) {
          const int bo = (g * 32 + llo) * 72 + ks * 16 + lhi * 8;
          const bh8 bhv = *(const bh8*)&U[SHo + bo];
          const bh8 blv = *(const bh8*)&U[SLo + bo];
          s2accum<0>(acc0, wsu, ks, lof, bhv, blv);
          s2accum<1>(acc1, wsu, ks, lof, bhv, blv);
        }
      } else {
#pragma unroll
        for (int e = 0; e < 16; ++e) acc0[e] = 0.f;
#pragma unroll
        for (int ks = 0; ks < 3; ++ks) {
          const int bo = (g * 32 + llo) * 72 + ks * 16 + lhi * 8;
          const bh8 bhv = *(const bh8*)&U[SHo + bo];
          const bh8 blv = *(const bh8*)&U[SLo + bo];
          s2accum<2>(acc0, wsu, ks, lof, bhv, blv);
        }
      }
    }
    __syncthreads();
    if (act) {
      if (r == 0) {
        writes_s(U, acc0, 0, g, llo, lhi);
        writes_s(U, acc1, 1, g, llo, lhi);
      } else {
        writes_s(U, acc0, 2, g, llo, lhi);
      }
    }
  }
  __syncthreads();

  // ---- (d) stage3 MFMA, shared s reads: wave mtO owns all 3 ntK accumulators.
  if (wv < nt16) {
    const int mtO = wv;
    f4v a0, a1, a2;
    a0[0] = a0[1] = a0[2] = a0[3] = 0.f;
    a1[0] = a1[1] = a1[2] = a1[3] = 0.f;
    a2[0] = a2[1] = a2[2] = a2[3] = 0.f;
#pragma unroll
    for (int sl = 0; sl < 3; ++sl) {
      const int ao = (mtO * 16 + l15) * 104 + sl * 32 + q4 * 8;
      const bh8 ah = *(const bh8*)&U[SHo + ao];
      const bh8 al = *(const bh8*)&U[SLo + ao];
      d3accum<0>(a0, wsu, sl, lof, ah, al);
      d3accum<1>(a1, wsu, sl, lof, ah, al);
      d3accum<2>(a2, wsu, sl, lof, ah, al);
    }
    const int oc = mtO * 16 + q4 * 4;
    split_store4(&U[XHo + l15 * 72 + oc], &U[XLo + l15 * 72 + oc],
                 a0[0], a0[1], a0[2], a0[3]);
    split_store4(&U[XHo + (16 + l15) * 72 + oc], &U[XLo + (16 + l15) * 72 + oc],
                 a1[0], a1[1], a1[2], a1[3]);
    split_store4(&U[XHo + (32 + l15) * 72 + oc], &U[XLo + (32 + l15) * 72 + oc],
                 a2[0], a2[1], a2[2], a2[3]);
  }
  __syncthreads();
}

// ======================= main kernel =======================
__global__ __launch_bounds__(NT, 8)
void scnn_main(const float* __restrict__ xin, const unsigned short* __restrict__ wsu,
               float* __restrict__ out) {
  __shared__ __align__(16) unsigned short U[NU];
  const int tid = threadIdx.x, b = blockIdx.x;
  const int lane = tid & 63, wv = tid >> 6;
  const int llo = lane & 31, lhi = lane >> 5;
  const int l15 = lane & 15, q4 = lane >> 4;
  const int lof = lane << 3;

  // ---- stage initial X: [k][c] stride 72, cols 0..7 (cin=4 + pad), scale-folded
  for (int i = tid; i < 384; i += NT) {
    const int k = i >> 3, c = i & 7;
    float v = 0.f;
    if (c < 4 && k < 45) v = xin[(size_t)b * 180 + c * 45 + k] * scale_from_j(lidxf(k));
    const unsigned u = __float_as_uint(v);
    const unsigned short h = (unsigned short)(u >> 16);
    U[XHo + k * 72 + c] = h;
    U[XLo + k * 72 + c] = f2bf(v - bf2f(h));
  }
  if (tid < 8) U[ZOFF + tid] = 0;  // zero block for OOB A-frag reads
  __syncthreads();

  layer_body<0>(U, wsu, tid, wv, llo, lhi, l15, q4, lof);
  layer_body<1>(U, wsu, tid, wv, llo, lhi, l15, q4, lof);
  layer_body<2>(U, wsu, tid, wv, llo, lhi, l15, q4, lof);
  layer_body<3>(U, wsu, tid, wv, llo, lhi, l15, q4, lof);
  layer_body<4>(U, wsu, tid, wv, llo, lhi, l15, q4, lof);
  layer_body<5>(U, wsu, tid, wv, llo, lhi, l15, q4, lof);

  // ---- epilogue: out[b][c][k] = (XH+XL)[k][c] * (1/scale[k])
  for (int i = tid; i < 180; i += NT) {
    const int c = i / 45, k = i - c * 45;
    const float v = bf2f(U[XHo + k * 72 + c]) + bf2f(U[XLo + k * 72 + c]);
    out[(size_t)b * 180 + i] = v * rcp_from_j(lidxf(k));
  }
}

extern "C" void kernel_launch(void* const* d_in, const int* in_sizes, int n_in,
                              void* d_out, int out_size, void* d_ws, size_t ws_size,
                              hipStream_t stream) {
  (void)n_in; (void)out_size; (void)ws_size;
  const float* x    = (const float*)d_in[0];
  const float* sft  = (const float*)d_in[1];
  const float* isft = (const float*)d_in[2];
  const float* w1   = (const float*)d_in[3];
  const float* w2   = (const float*)d_in[4];
  const float* w3   = (const float*)d_in[5];
  const float* w4   = (const float*)d_in[6];
  const float* w5   = (const float*)d_in[7];
  const float* w6   = (const float*)d_in[8];
  float* out = (float*)d_out;
  unsigned short* wsu = (unsigned short*)d_ws;  // uses 151552 B of scratch
  const int nb = in_sizes[0] / 180;             // 50000
  scnn_prep<<<64, NT, 0, stream>>>(sft, isft, w1, w2, w3, w4, w5, w6, wsu);
  scnn_main<<<nb, NT, 0, stream>>>(x, wsu, out);
}

// Round 5
// 1067.887 us; speedup vs baseline: 1.3680x; 1.3680x over previous
//
#include <hip/hip_runtime.h>

#define NT 512

typedef __attribute__((ext_vector_type(8)))  short bh8;   // 8 bf16
typedef __attribute__((ext_vector_type(16))) float f16v;  // 32x32 acc
typedef __attribute__((ext_vector_type(4)))  float f4v;   // 16x16 acc

// ---- d_ws layout (ushort units): pre-swizzled 64-lane x 16B fragment dumps.
// Every frag is 512 ush (1KB); a wave loads it as base + lane*8 (fully coalesced).
#define FW_H    0      // sconv expanded-weight B-frags, 56 frags (28672)
#define FW_L    28672
#define W2A32_H 57344  // stage2 32x32 A-frags (isft), 9 frags (4608)
#define W2A32_L 61952
#define W3B_H   66560  // stage3 B-frags (scale*sft), 9 frags (4608)
#define W3B_L   71168  // end 75776 ush = 151552 B

// ---- LDS layout (ushort units): activations only ----
#define SHo  0      // s planes [o][p] stride 104 (6656); overlay: y planes [o][k] stride 72
#define SLo  6656
#define XHo  13312  // x planes [k][c] stride 72 (3456)
#define XLo  16768
#define ZOFF 20224  // 8-ush zero block for OOB sconv A-frag reads
#define NU   20232  // 40464 B -> 4 blocks/CU (with 512 thr: 32 waves/CU)

__device__ __forceinline__ unsigned short f2bf(float f) {  // RNE
  unsigned u = __float_as_uint(f);
  return (unsigned short)((u + 0x7fffu + ((u >> 16) & 1u)) >> 16);
}
__device__ __forceinline__ float bf2f(unsigned short h) {
  return __uint_as_float(((unsigned)h) << 16);
}
__device__ __forceinline__ int lidxf(int k) {  // degree band l/2 for coeff k
  return (k < 1) ? 0 : (k < 6) ? 1 : (k < 15) ? 2 : (k < 28) ? 3 : 4;
}
__device__ __forceinline__ float scale_from_j(int j) {  // sqrt(pi/(4j+1))
  float s = 1.7724539f;
  s = (j == 1) ? 0.79266548f : s;
  s = (j == 2) ? 0.59081795f : s;
  s = (j == 3) ? 0.49159026f : s;
  s = (j >= 4) ? 0.42988324f : s;
  return s;
}
__device__ __forceinline__ float rcp_from_j(int j) {  // 1/scale
  float s = 0.56418958f;
  s = (j == 1) ? 1.2615663f : s;
  s = (j == 2) ? 1.6925688f : s;
  s = (j == 3) ? 2.0342144f : s;
  s = (j >= 4) ? 2.3262120f : s;
  return s;
}
// packed split: hi = trunc-bf16 pair via v_perm; lo = trunc(v - bf2f(hi)) pair
__device__ __forceinline__ unsigned pk_hi(float a, float b) {
  return __builtin_amdgcn_perm(__float_as_uint(b), __float_as_uint(a), 0x07060302u);
}
__device__ __forceinline__ void split_store4(unsigned short* dh, unsigned short* dl,
                                             float v0, float v1, float v2, float v3) {
  const unsigned u0 = __float_as_uint(v0), u1 = __float_as_uint(v1);
  const unsigned u2 = __float_as_uint(v2), u3 = __float_as_uint(v3);
  const float d0 = v0 - __uint_as_float(u0 & 0xffff0000u);
  const float d1 = v1 - __uint_as_float(u1 & 0xffff0000u);
  const float d2 = v2 - __uint_as_float(u2 & 0xffff0000u);
  const float d3 = v3 - __uint_as_float(u3 & 0xffff0000u);
  *(uint2*)dh = make_uint2(pk_hi(v0, v1), pk_hi(v2, v3));
  *(uint2*)dl = make_uint2(pk_hi(d0, d1), pk_hi(d2, d3));
}

// ======================= pre-kernel: build fragment dumps =======================
__global__ void scnn_prep(const float* __restrict__ sft, const float* __restrict__ isft,
                          const float* __restrict__ w1, const float* __restrict__ w2,
                          const float* __restrict__ w3, const float* __restrict__ w4,
                          const float* __restrict__ w5, const float* __restrict__ w6,
                          unsigned short* __restrict__ wsu) {
  const int gid = blockIdx.x * NT + threadIdx.x;
  const int gstr = gridDim.x * NT;
  const float* wp[6] = {w1, w2, w3, w4, w5, w6};
  const int CIN[6] = {4, 16, 32, 64, 32, 16};
  const int COUT[6] = {16, 32, 64, 32, 16, 4};
  const int LG[6] = {3, 4, 5, 6, 5, 4};
  const int NST[6] = {2, 3, 5, 10, 5, 3};
  const int NTC[6] = {1, 2, 4, 2, 1, 1};
  const int FOFF[6] = {0, 2, 8, 28, 48, 53};
#pragma unroll
  for (int l = 0; l < 6; ++l) {
    const int cin = CIN[l], cout = COUT[l], lg = LG[l], cinP = 1 << lg;
    const int nst = NST[l];
    const int n = NTC[l] * nst * 512;
    const float* w = wp[l];
    const int base = FOFF[l] * 512;
    for (int i = gid; i < n; i += gstr) {
      const int fid = i >> 9, lane = (i >> 3) & 63, e = i & 7;
      const int nt = fid / nst, st = fid - nt * nst;
      const int o = nt * 16 + (lane & 15);
      const int s = st * 32 + (lane >> 4) * 8 + e;
      const int j = s >> lg, c = s & (cinP - 1);
      float v = 0.f;
      if (o < cout && j < 5 && c < cin) v = w[(o * cin + c) * 5 + j];
      const unsigned short h = f2bf(v);
      wsu[FW_H + base + i] = h;
      wsu[FW_L + base + i] = f2bf(v - bf2f(h));
    }
  }
  for (int i = gid; i < 9 * 512; i += gstr) {  // stage2 32x32 A-frags (isft)
    const int fid = i >> 9, lane = (i >> 3) & 63, e = i & 7;
    const int mt = fid / 3, ks = fid - mt * 3;
    const int p = mt * 32 + (lane & 31);
    const int k = ks * 16 + (lane >> 5) * 8 + e;
    const float v = (p < 90 && k < 45) ? isft[p * 45 + k] : 0.f;
    const unsigned short h = f2bf(v);
    wsu[W2A32_H + i] = h;
    wsu[W2A32_L + i] = f2bf(v - bf2f(h));
  }
  for (int i = gid; i < 9 * 512; i += gstr) {  // stage3 B-frags (scale*sft)
    const int fid = i >> 9, lane = (i >> 3) & 63, e = i & 7;
    const int ntK = fid / 3, sl = fid - ntK * 3;
    const int kk = ntK * 16 + (lane & 15);
    const int p = sl * 32 + (lane >> 4) * 8 + e;
    float v = 0.f;
    if (kk < 45 && p < 90) v = sft[kk * 90 + p] * scale_from_j(lidxf(kk));
    const unsigned short h = f2bf(v);
    wsu[W3B_H + i] = h;
    wsu[W3B_L + i] = f2bf(v - bf2f(h));
  }
}

// stage2 tile: C[m=p][n=o] += sum_k WI[p][k]*y[o][k], 32x32x16, K=48.
// Single accumulator: all three split products chain through C (f32 accumulate).
__device__ __forceinline__ f16v s2tile(const unsigned short* U,
                                       const unsigned short* __restrict__ wsu,
                                       int mt, int nt, int llo, int lhi, int lof) {
  f16v a;
#pragma unroll
  for (int e = 0; e < 16; ++e) a[e] = 0.f;
  const unsigned short* fh = wsu + W2A32_H + mt * 3 * 512 + lof;
#pragma unroll
  for (int ks = 0; ks < 3; ++ks) {
    const bh8 ah = *(const bh8*)&fh[ks * 512];
    const bh8 al = *(const bh8*)&fh[(W2A32_L - W2A32_H) + ks * 512];
    const int bo = (nt * 32 + llo) * 72 + ks * 16 + lhi * 8;
    const bh8 bhv = *(const bh8*)&U[SHo + bo];  // y overlay, stride 72
    const bh8 blv = *(const bh8*)&U[SLo + bo];
    a = __builtin_amdgcn_mfma_f32_32x32x16_bf16(ah, bhv, a, 0, 0, 0);
    a = __builtin_amdgcn_mfma_f32_32x32x16_bf16(al, bhv, a, 0, 0, 0);
    a = __builtin_amdgcn_mfma_f32_32x32x16_bf16(ah, blv, a, 0, 0, 0);
  }
  return a;
}
__device__ __forceinline__ void writes_s(unsigned short* U, f16v acc, int mt,
                                         int nt, int llo, int lhi) {
  const int o = nt * 32 + llo;
#pragma unroll
  for (int g = 0; g < 4; ++g) {
    const int p0 = mt * 32 + g * 8 + lhi * 4;
    split_store4(&U[SHo + o * 104 + p0], &U[SLo + o * 104 + p0],
                 fmaxf(acc[g * 4 + 0], 0.f), fmaxf(acc[g * 4 + 1], 0.f),
                 fmaxf(acc[g * 4 + 2], 0.f), fmaxf(acc[g * 4 + 3], 0.f));
  }
}

// stage3 partial: accumulate one ntK (k'-tile) into acc given shared s operands.
template <int NTK>
__device__ __forceinline__ void d3accum(f4v& a, const unsigned short* __restrict__ wsu,
                                        int sl, int lof, bh8 ah, bh8 al) {
  const unsigned short* fb = wsu + W3B_H + (NTK * 3 + sl) * 512 + lof;
  const bh8 bhv = *(const bh8*)&fb[0];
  const bh8 blv = *(const bh8*)&fb[W3B_L - W3B_H];
  a = __builtin_amdgcn_mfma_f32_16x16x32_bf16(ah, bhv, a, 0, 0, 0);
  a = __builtin_amdgcn_mfma_f32_16x16x32_bf16(al, bhv, a, 0, 0, 0);
  a = __builtin_amdgcn_mfma_f32_16x16x32_bf16(ah, blv, a, 0, 0, 0);
}

// ---- stage (a) tile(s): wave owns nt-pair {n0, n0+na-1} (na<=2, named accs);
// X-operand LDS reads shared across the pair. unroll 2 caps in-flight loads.
template <int layer, int mt, int n0, int na>
__device__ __forceinline__ void atile2(unsigned short* U,
                                       const unsigned short* __restrict__ wsu,
                                       int l15, int q4, int lof) {
  constexpr int lg   = (layer == 0) ? 3 : (layer == 1) ? 4 : (layer == 2) ? 5
                     : (layer == 3) ? 6 : (layer == 4) ? 5 : 4;
  constexpr int cinP = 1 << lg;
  constexpr int NSTc = (layer == 0) ? 2 : (layer == 1) ? 3 : (layer == 2) ? 5
                     : (layer == 3) ? 10 : (layer == 4) ? 5 : 3;
  constexpr int FOFFc= (layer == 0) ? 0 : (layer == 1) ? 2 : (layer == 2) ? 8
                     : (layer == 3) ? 28 : (layer == 4) ? 48 : 53;
  constexpr int hi5 = (5 * cinP + 31) >> 5;
  constexpr int hi4 = (4 * cinP + 31) >> 5;
  constexpr int lo3 = (3 * cinP) >> 5;
  constexpr int lo4 = cinP >> 3;
  constexpr int lo = (mt == 0) ? 0 : (mt == 1) ? lo3 : lo4;
  constexpr int hi = (mt == 0) ? hi4 : hi5;

  const int k = mt * 16 + l15;
  const int jb = lidxf(k) << lg;
  f4v a0, a1;
  a0[0] = a0[1] = a0[2] = a0[3] = 0.f;
  a1[0] = a1[1] = a1[2] = a1[3] = 0.f;
#pragma unroll 2
  for (int st = lo; st < hi; ++st) {
    const int S = st * 32 + q4 * 8;
    const unsigned c0 = (unsigned)(S - jb);
    const int base = XHo + k * 72 + (int)(c0 & 56u);
    const bool oob = c0 >= (unsigned)cinP;
    const int axh = oob ? ZOFF : base;
    const int axl = oob ? ZOFF : (base + (XLo - XHo));
    const bh8 xh = *(const bh8*)&U[axh];
    const bh8 xl = *(const bh8*)&U[axl];
    {
      const unsigned short* wf = wsu + FW_H + (FOFFc + n0 * NSTc + st) * 512 + lof;
      const bh8 wh = *(const bh8*)&wf[0];
      const bh8 wl = *(const bh8*)&wf[FW_L - FW_H];
      a0 = __builtin_amdgcn_mfma_f32_16x16x32_bf16(xh, wh, a0, 0, 0, 0);
      a0 = __builtin_amdgcn_mfma_f32_16x16x32_bf16(xl, wh, a0, 0, 0, 0);
      a0 = __builtin_amdgcn_mfma_f32_16x16x32_bf16(xh, wl, a0, 0, 0, 0);
    }
    if constexpr (na > 1) {
      const unsigned short* wf = wsu + FW_H + (FOFFc + (n0 + 1) * NSTc + st) * 512 + lof;
      const bh8 wh = *(const bh8*)&wf[0];
      const bh8 wl = *(const bh8*)&wf[FW_L - FW_H];
      a1 = __builtin_amdgcn_mfma_f32_16x16x32_bf16(xh, wh, a1, 0, 0, 0);
      a1 = __builtin_amdgcn_mfma_f32_16x16x32_bf16(xl, wh, a1, 0, 0, 0);
      a1 = __builtin_amdgcn_mfma_f32_16x16x32_bf16(xh, wl, a1, 0, 0, 0);
    }
  }
  const int kq = mt * 16 + q4 * 4;
  {
    const int o = n0 * 16 + l15;
    split_store4(&U[SHo + o * 72 + kq], &U[SLo + o * 72 + kq],
                 a0[0], a0[1], a0[2], a0[3]);
  }
  if constexpr (na > 1) {
    const int o = (n0 + 1) * 16 + l15;
    split_store4(&U[SHo + o * 72 + kq], &U[SLo + o * 72 + kq],
                 a1[0], a1[1], a1[2], a1[3]);
  }
}

// ======================= per-layer body (compile-time specialized) =======
template <int layer>
__device__ __forceinline__ void layer_body(unsigned short* U,
                                           const unsigned short* __restrict__ wsu,
                                           int tid, int wv, int llo, int lhi,
                                           int l15, int q4, int lof) {
  constexpr int nt16 = (layer == 2) ? 4 : (layer == 1 || layer == 3) ? 2 : 1;
  constexpr int n32  = (layer == 2) ? 2 : 1;

  // ---- (a) sconv via MFMA: wave = mt (x nt-half for layer 2), shared X reads
  if constexpr (nt16 == 1) {
    if (wv == 0)      atile2<layer, 0, 0, 1>(U, wsu, l15, q4, lof);
    else if (wv == 1) atile2<layer, 1, 0, 1>(U, wsu, l15, q4, lof);
    else if (wv == 2) atile2<layer, 2, 0, 1>(U, wsu, l15, q4, lof);
  } else if constexpr (nt16 == 2) {
    if (wv == 0)      atile2<layer, 0, 0, 2>(U, wsu, l15, q4, lof);
    else if (wv == 1) atile2<layer, 1, 0, 2>(U, wsu, l15, q4, lof);
    else if (wv == 2) atile2<layer, 2, 0, 2>(U, wsu, l15, q4, lof);
  } else {  // layer 2: 6 waves, each an nt-pair
    if (wv == 0)      atile2<layer, 0, 0, 2>(U, wsu, l15, q4, lof);
    else if (wv == 1) atile2<layer, 1, 0, 2>(U, wsu, l15, q4, lof);
    else if (wv == 2) atile2<layer, 2, 0, 2>(U, wsu, l15, q4, lof);
    else if (wv == 4) atile2<layer, 0, 2, 2>(U, wsu, l15, q4, lof);
    else if (wv == 5) atile2<layer, 1, 2, 2>(U, wsu, l15, q4, lof);
    else if (wv == 6) atile2<layer, 2, 2, 2>(U, wsu, l15, q4, lof);
  }
  __syncthreads();

  // ---- (b)+(c) stage2 MFMA (round-3 form: one f16v per wave, acc across barrier)
  {
    constexpr int T2 = 3 * n32;  // <= 6 < 8 waves: one tile per wave
    const bool hA = wv < T2;
    f16v a0;
    if (hA) a0 = s2tile(U, wsu, wv % 3, wv / 3, llo, lhi, lof);
    __syncthreads();
    if (hA) writes_s(U, a0, wv % 3, wv / 3, llo, lhi);
  }
  __syncthreads();

  // ---- (d) stage3 MFMA, shared s reads: wv&3 = mtO; wv>>2 = ntK group
  //      grp 0: ntK{0,1} (two f4v accs), grp 1: ntK{2}. 2*nt16 active waves.
  {
    const int grp = wv >> 2, mtO = wv & 3;
    if (mtO < nt16) {
      const int oc = mtO * 16 + q4 * 4;
      if (grp == 0) {
        f4v a0, a1;
        a0[0] = a0[1] = a0[2] = a0[3] = 0.f;
        a1[0] = a1[1] = a1[2] = a1[3] = 0.f;
#pragma unroll
        for (int sl = 0; sl < 3; ++sl) {
          const int ao = (mtO * 16 + l15) * 104 + sl * 32 + q4 * 8;
          const bh8 ah = *(const bh8*)&U[SHo + ao];
          const bh8 al = *(const bh8*)&U[SLo + ao];
          d3accum<0>(a0, wsu, sl, lof, ah, al);
          d3accum<1>(a1, wsu, sl, lof, ah, al);
        }
        split_store4(&U[XHo + l15 * 72 + oc], &U[XLo + l15 * 72 + oc],
                     a0[0], a0[1], a0[2], a0[3]);
        split_store4(&U[XHo + (16 + l15) * 72 + oc], &U[XLo + (16 + l15) * 72 + oc],
                     a1[0], a1[1], a1[2], a1[3]);
      } else {
        f4v a2;
        a2[0] = a2[1] = a2[2] = a2[3] = 0.f;
#pragma unroll
        for (int sl = 0; sl < 3; ++sl) {
          const int ao = (mtO * 16 + l15) * 104 + sl * 32 + q4 * 8;
          const bh8 ah = *(const bh8*)&U[SHo + ao];
          const bh8 al = *(const bh8*)&U[SLo + ao];
          d3accum<2>(a2, wsu, sl, lof, ah, al);
        }
        split_store4(&U[XHo + (32 + l15) * 72 + oc], &U[XLo + (32 + l15) * 72 + oc],
                     a2[0], a2[1], a2[2], a2[3]);
      }
    }
  }
  __syncthreads();
}

// ======================= main kernel =======================
__global__ __launch_bounds__(NT, 8)
void scnn_main(const float* __restrict__ xin, const unsigned short* __restrict__ wsu,
               float* __restrict__ out) {
  __shared__ __align__(16) unsigned short U[NU];
  const int tid = threadIdx.x, b = blockIdx.x;
  const int lane = tid & 63, wv = tid >> 6;
  const int llo = lane & 31, lhi = lane >> 5;
  const int l15 = lane & 15, q4 = lane >> 4;
  const int lof = lane << 3;

  // ---- stage initial X: [k][c] stride 72, cols 0..7 (cin=4 + pad), scale-folded
  for (int i = tid; i < 384; i += NT) {
    const int k = i >> 3, c = i & 7;
    float v = 0.f;
    if (c < 4 && k < 45) v = xin[(size_t)b * 180 + c * 45 + k] * scale_from_j(lidxf(k));
    const unsigned u = __float_as_uint(v);
    const unsigned short h = (unsigned short)(u >> 16);
    U[XHo + k * 72 + c] = h;
    U[XLo + k * 72 + c] = f2bf(v - bf2f(h));
  }
  if (tid < 8) U[ZOFF + tid] = 0;  // zero block for OOB A-frag reads
  __syncthreads();

  layer_body<0>(U, wsu, tid, wv, llo, lhi, l15, q4, lof);
  layer_body<1>(U, wsu, tid, wv, llo, lhi, l15, q4, lof);
  layer_body<2>(U, wsu, tid, wv, llo, lhi, l15, q4, lof);
  layer_body<3>(U, wsu, tid, wv, llo, lhi, l15, q4, lof);
  layer_body<4>(U, wsu, tid, wv, llo, lhi, l15, q4, lof);
  layer_body<5>(U, wsu, tid, wv, llo, lhi, l15, q4, lof);

  // ---- epilogue: out[b][c][k] = (XH+XL)[k][c] * (1/scale[k])
  for (int i = tid; i < 180; i += NT) {
    const int c = i / 45, k = i - c * 45;
    const float v = bf2f(U[XHo + k * 72 + c]) + bf2f(U[XLo + k * 72 + c]);
    out[(size_t)b * 180 + i] = v * rcp_from_j(lidxf(k));
  }
}

extern "C" void kernel_launch(void* const* d_in, const int* in_sizes, int n_in,
                              void* d_out, int out_size, void* d_ws, size_t ws_size,
                              hipStream_t stream) {
  (void)n_in; (void)out_size; (void)ws_size;
  const float* x    = (const float*)d_in[0];
  const float* sft  = (const float*)d_in[1];
  const float* isft = (const float*)d_in[2];
  const float* w1   = (const float*)d_in[3];
  const float* w2   = (const float*)d_in[4];
  const float* w3   = (const float*)d_in[5];
  const float* w4   = (const float*)d_in[6];
  const float* w5   = (const float*)d_in[7];
  const float* w6   = (const float*)d_in[8];
  float* out = (float*)d_out;
  unsigned short* wsu = (unsigned short*)d_ws;  // uses 151552 B of scratch
  const int nb = in_sizes[0] / 180;             // 50000
  scnn_prep<<<64, NT, 0, stream>>>(sft, isft, w1, w2, w3, w4, w5, w6, wsu);
  scnn_main<<<nb, NT, 0, stream>>>(x, wsu, out);
}

// Round 6
// 1014.679 us; speedup vs baseline: 1.4397x; 1.0524x over previous
//
#include <hip/hip_runtime.h>

#define NT 512

typedef __attribute__((ext_vector_type(8)))  short bh8;   // 8 bf16
typedef __attribute__((ext_vector_type(16))) float f16v;  // 32x32 acc
typedef __attribute__((ext_vector_type(4)))  float f4v;   // 16x16 acc

// ---- d_ws layout (ushort units): pre-swizzled 64-lane x 16B fragment dumps.
// Every frag is 512 ush (1KB); a wave loads it as base + lane*8 (fully coalesced).
#define FW_H    0      // sconv expanded-weight B-frags, 56 frags (28672)
#define FW_L    28672
#define W2A32_H 57344  // stage2 32x32 A-frags (isft), 9 frags (4608)
#define W2A32_L 61952
#define W3B_H   66560  // stage3 B-frags (scale*sft), 9 frags (4608)
#define W3B_L   71168  // end 75776 ush = 151552 B

// ---- LDS layout (ushort units): activations only ----
// X planes are kept FULLY ZERO outside live columns: prologue zero-fills the
// whole region; stage (d) writes live cols [0,16*nt16) and re-zeroes the
// stale cols the next layer's OOB window can see (L3: 32-63, L4: 16-31).
// Cols 64-71 are never written -> OOB clamp to col 64 reads zeros.
#define SHo  0      // s planes [o][p] stride 104 (6656); overlay: y planes [o][k] stride 72
#define SLo  6656
#define XHo  13312  // x planes [k][c] stride 72 (3456)
#define XLo  16768
#define NU   20232  // 40464 B -> 4 blocks/CU (with 512 thr: 32 waves/CU)

__device__ __forceinline__ unsigned short f2bf(float f) {  // RNE
  unsigned u = __float_as_uint(f);
  return (unsigned short)((u + 0x7fffu + ((u >> 16) & 1u)) >> 16);
}
__device__ __forceinline__ float bf2f(unsigned short h) {
  return __uint_as_float(((unsigned)h) << 16);
}
__device__ __forceinline__ int lidxf(int k) {  // degree band l/2 for coeff k
  return (k < 1) ? 0 : (k < 6) ? 1 : (k < 15) ? 2 : (k < 28) ? 3 : 4;
}
__device__ __forceinline__ float scale_from_j(int j) {  // sqrt(pi/(4j+1))
  float s = 1.7724539f;
  s = (j == 1) ? 0.79266548f : s;
  s = (j == 2) ? 0.59081795f : s;
  s = (j == 3) ? 0.49159026f : s;
  s = (j >= 4) ? 0.42988324f : s;
  return s;
}
__device__ __forceinline__ float rcp_from_j(int j) {  // 1/scale
  float s = 0.56418958f;
  s = (j == 1) ? 1.2615663f : s;
  s = (j == 2) ? 1.6925688f : s;
  s = (j == 3) ? 2.0342144f : s;
  s = (j >= 4) ? 2.3262120f : s;
  return s;
}
// packed split: hi = trunc-bf16 pair via v_perm; lo = trunc(v - bf2f(hi)) pair
__device__ __forceinline__ unsigned pk_hi(float a, float b) {
  return __builtin_amdgcn_perm(__float_as_uint(b), __float_as_uint(a), 0x07060302u);
}
__device__ __forceinline__ void split_store4(unsigned short* dh, unsigned short* dl,
                                             float v0, float v1, float v2, float v3) {
  const unsigned u0 = __float_as_uint(v0), u1 = __float_as_uint(v1);
  const unsigned u2 = __float_as_uint(v2), u3 = __float_as_uint(v3);
  const float d0 = v0 - __uint_as_float(u0 & 0xffff0000u);
  const float d1 = v1 - __uint_as_float(u1 & 0xffff0000u);
  const float d2 = v2 - __uint_as_float(u2 & 0xffff0000u);
  const float d3 = v3 - __uint_as_float(u3 & 0xffff0000u);
  *(uint2*)dh = make_uint2(pk_hi(v0, v1), pk_hi(v2, v3));
  *(uint2*)dl = make_uint2(pk_hi(d0, d1), pk_hi(d2, d3));
}

// ======================= pre-kernel: build fragment dumps =======================
__global__ void scnn_prep(const float* __restrict__ sft, const float* __restrict__ isft,
                          const float* __restrict__ w1, const float* __restrict__ w2,
                          const float* __restrict__ w3, const float* __restrict__ w4,
                          const float* __restrict__ w5, const float* __restrict__ w6,
                          unsigned short* __restrict__ wsu) {
  const int gid = blockIdx.x * NT + threadIdx.x;
  const int gstr = gridDim.x * NT;
  const float* wp[6] = {w1, w2, w3, w4, w5, w6};
  const int CIN[6] = {4, 16, 32, 64, 32, 16};
  const int COUT[6] = {16, 32, 64, 32, 16, 4};
  const int LG[6] = {3, 4, 5, 6, 5, 4};
  const int NST[6] = {2, 3, 5, 10, 5, 3};
  const int NTC[6] = {1, 2, 4, 2, 1, 1};
  const int FOFF[6] = {0, 2, 8, 28, 48, 53};
#pragma unroll
  for (int l = 0; l < 6; ++l) {
    const int cin = CIN[l], cout = COUT[l], lg = LG[l], cinP = 1 << lg;
    const int nst = NST[l];
    const int n = NTC[l] * nst * 512;
    const float* w = wp[l];
    const int base = FOFF[l] * 512;
    for (int i = gid; i < n; i += gstr) {
      const int fid = i >> 9, lane = (i >> 3) & 63, e = i & 7;
      const int nt = fid / nst, st = fid - nt * nst;
      const int o = nt * 16 + (lane & 15);
      const int s = st * 32 + (lane >> 4) * 8 + e;
      const int j = s >> lg, c = s & (cinP - 1);
      float v = 0.f;
      if (o < cout && j < 5 && c < cin) v = w[(o * cin + c) * 5 + j];
      const unsigned short h = f2bf(v);
      wsu[FW_H + base + i] = h;
      wsu[FW_L + base + i] = f2bf(v - bf2f(h));
    }
  }
  for (int i = gid; i < 9 * 512; i += gstr) {  // stage2 32x32 A-frags (isft)
    const int fid = i >> 9, lane = (i >> 3) & 63, e = i & 7;
    const int mt = fid / 3, ks = fid - mt * 3;
    const int p = mt * 32 + (lane & 31);
    const int k = ks * 16 + (lane >> 5) * 8 + e;
    const float v = (p < 90 && k < 45) ? isft[p * 45 + k] : 0.f;
    const unsigned short h = f2bf(v);
    wsu[W2A32_H + i] = h;
    wsu[W2A32_L + i] = f2bf(v - bf2f(h));
  }
  for (int i = gid; i < 9 * 512; i += gstr) {  // stage3 B-frags (scale*sft)
    const int fid = i >> 9, lane = (i >> 3) & 63, e = i & 7;
    const int ntK = fid / 3, sl = fid - ntK * 3;
    const int kk = ntK * 16 + (lane & 15);
    const int p = sl * 32 + (lane >> 4) * 8 + e;
    float v = 0.f;
    if (kk < 45 && p < 90) v = sft[kk * 90 + p] * scale_from_j(lidxf(kk));
    const unsigned short h = f2bf(v);
    wsu[W3B_H + i] = h;
    wsu[W3B_L + i] = f2bf(v - bf2f(h));
  }
}

// stage2 tile: C[m=p][n=o] += sum_k WI[p][k]*y[o][k], 32x32x16, K=48.
// Single accumulator: all three split products chain through C (f32 accumulate).
__device__ __forceinline__ f16v s2tile(const unsigned short* U,
                                       const unsigned short* __restrict__ wsu,
                                       int mt, int nt, int llo, int lhi, int lof) {
  f16v a;
#pragma unroll
  for (int e = 0; e < 16; ++e) a[e] = 0.f;
  const unsigned short* fh = wsu + W2A32_H + mt * 3 * 512 + lof;
#pragma unroll
  for (int ks = 0; ks < 3; ++ks) {
    const bh8 ah = *(const bh8*)&fh[ks * 512];
    const bh8 al = *(const bh8*)&fh[(W2A32_L - W2A32_H) + ks * 512];
    const int bo = (nt * 32 + llo) * 72 + ks * 16 + lhi * 8;
    const bh8 bhv = *(const bh8*)&U[SHo + bo];  // y overlay, stride 72
    const bh8 blv = *(const bh8*)&U[SLo + bo];
    a = __builtin_amdgcn_mfma_f32_32x32x16_bf16(ah, bhv, a, 0, 0, 0);
    a = __builtin_amdgcn_mfma_f32_32x32x16_bf16(al, bhv, a, 0, 0, 0);
    a = __builtin_amdgcn_mfma_f32_32x32x16_bf16(ah, blv, a, 0, 0, 0);
  }
  return a;
}
__device__ __forceinline__ void writes_s(unsigned short* U, f16v acc, int mt,
                                         int nt, int llo, int lhi) {
  const int o = nt * 32 + llo;
#pragma unroll
  for (int g = 0; g < 4; ++g) {
    const int p0 = mt * 32 + g * 8 + lhi * 4;
    split_store4(&U[SHo + o * 104 + p0], &U[SLo + o * 104 + p0],
                 fmaxf(acc[g * 4 + 0], 0.f), fmaxf(acc[g * 4 + 1], 0.f),
                 fmaxf(acc[g * 4 + 2], 0.f), fmaxf(acc[g * 4 + 3], 0.f));
  }
}

// ---- stage (a) tile, mt compile-time: constant st-window -> full unroll.
// OOB columns clamp to col 64 (always-zero pad) instead of a cndmask redirect:
// X region is zero outside live columns by construction.
template <int layer, int mt>
__device__ __forceinline__ void atile(unsigned short* U,
                                      const unsigned short* __restrict__ wsu,
                                      int nt, int l15, int q4, int lof) {
  constexpr int lg   = (layer == 0) ? 3 : (layer == 1) ? 4 : (layer == 2) ? 5
                     : (layer == 3) ? 6 : (layer == 4) ? 5 : 4;
  constexpr int cinP = 1 << lg;
  constexpr int NSTc = (layer == 0) ? 2 : (layer == 1) ? 3 : (layer == 2) ? 5
                     : (layer == 3) ? 10 : (layer == 4) ? 5 : 3;
  constexpr int FOFFc= (layer == 0) ? 0 : (layer == 1) ? 2 : (layer == 2) ? 8
                     : (layer == 3) ? 28 : (layer == 4) ? 48 : 53;
  constexpr int hi5 = (5 * cinP + 31) >> 5;
  constexpr int hi4 = (4 * cinP + 31) >> 5;
  constexpr int lo3 = (3 * cinP) >> 5;
  constexpr int lo4 = cinP >> 3;
  constexpr int lo = (mt == 0) ? 0 : (mt == 1) ? lo3 : lo4;
  constexpr int hi = (mt == 0) ? hi4 : hi5;
  (void)cinP;

  const int k = mt * 16 + l15;
  const int jb = lidxf(k) << lg;
  const unsigned short* wfh = wsu + FW_H + (FOFFc + nt * NSTc) * 512 + lof;
  f4v a;
  a[0] = a[1] = a[2] = a[3] = 0.f;
#pragma unroll
  for (int st = lo; st < hi; ++st) {
    const int S = st * 32 + q4 * 8;
    const unsigned c0 = (unsigned)(S - jb);
    const unsigned cc = c0 < 64u ? c0 : 64u;  // v_min_u32: OOB -> zero pad col
    const unsigned short* xp = &U[XHo + k * 72 + (int)cc];
    const bh8 xh = *(const bh8*)xp;
    const bh8 xl = *(const bh8*)(xp + (XLo - XHo));  // folds to ds_read offset
    const bh8 wh = *(const bh8*)&wfh[st * 512];
    const bh8 wl = *(const bh8*)&wfh[(FW_L - FW_H) + st * 512];
    a = __builtin_amdgcn_mfma_f32_16x16x32_bf16(xh, wh, a, 0, 0, 0);
    a = __builtin_amdgcn_mfma_f32_16x16x32_bf16(xl, wh, a, 0, 0, 0);
    a = __builtin_amdgcn_mfma_f32_16x16x32_bf16(xh, wl, a, 0, 0, 0);
  }
  // lane holds y[o][kq..kq+3] (C: col=o, rows consecutive k)
  const int o = nt * 16 + l15;
  const int kq = mt * 16 + q4 * 4;
  split_store4(&U[SHo + o * 72 + kq], &U[SLo + o * 72 + kq],
               a[0], a[1], a[2], a[3]);
}

// ======================= per-layer body (compile-time specialized) =======
// 8 waves per element: tile loops stride by 8 (round-3 wide distribution).
template <int layer>
__device__ __forceinline__ void layer_body(unsigned short* U,
                                           const unsigned short* __restrict__ wsu,
                                           int tid, int wv, int llo, int lhi,
                                           int l15, int q4, int lof) {
  constexpr int nt16 = (layer == 2) ? 4 : (layer == 1 || layer == 3) ? 2 : 1;
  constexpr int n32  = (layer == 2) ? 2 : 1;

  // ---- (a) sconv via MFMA, pre-swizzled weight frags; y [o][k] stride 72
  {
    constexpr int T = 3 * nt16;
    for (int t = wv; t < T; t += 8) {
      const int mt = t % 3, nt = t / 3;
      if (mt == 0)      atile<layer, 0>(U, wsu, nt, l15, q4, lof);
      else if (mt == 1) atile<layer, 1>(U, wsu, nt, l15, q4, lof);
      else              atile<layer, 2>(U, wsu, nt, l15, q4, lof);
    }
  }
  __syncthreads();

  // ---- (b)+(c) stage2 MFMA (32-path for ALL layers), acc in regs across barrier
  {
    constexpr int T2 = 3 * n32;  // <= 6 < 8 waves: one tile per wave
    const bool hA = wv < T2;
    f16v a0;
    if (hA) a0 = s2tile(U, wsu, wv % 3, wv / 3, llo, lhi, lof);
    __syncthreads();
    if (hA) writes_s(U, a0, wv % 3, wv / 3, llo, lhi);
  }
  __syncthreads();

  // ---- (d) stage3 MFMA: A = s (LDS), B = WS' frags (global).
  //      C[m=o][n=k']: lane k' fixed, o consecutive -> vector X[k'][o] writes.
  //      L3/L4 additionally re-zero the stale cols visible to the next layer.
  constexpr int T3 = 3 * nt16;
  for (int t = wv; t < T3; t += 8) {
    const int ntK = t % 3, mtO = t / 3;
    const unsigned short* fb = wsu + W3B_H + ntK * 3 * 512 + lof;
    f4v a;
    a[0] = a[1] = a[2] = a[3] = 0.f;
#pragma unroll
    for (int sl = 0; sl < 3; ++sl) {
      const int ao = (mtO * 16 + l15) * 104 + sl * 32 + q4 * 8;
      const bh8 ah = *(const bh8*)&U[SHo + ao];
      const bh8 al = *(const bh8*)&U[SLo + ao];
      const bh8 bhv = *(const bh8*)&fb[sl * 512];
      const bh8 blv = *(const bh8*)&fb[(W3B_L - W3B_H) + sl * 512];
      a = __builtin_amdgcn_mfma_f32_16x16x32_bf16(ah, bhv, a, 0, 0, 0);
      a = __builtin_amdgcn_mfma_f32_16x16x32_bf16(al, bhv, a, 0, 0, 0);
      a = __builtin_amdgcn_mfma_f32_16x16x32_bf16(ah, blv, a, 0, 0, 0);
    }
    const int kk = ntK * 16 + l15;     // k' row (fixed per lane)
    const int oc = mtO * 16 + q4 * 4;  // o columns (consecutive)
    split_store4(&U[XHo + kk * 72 + oc], &U[XLo + kk * 72 + oc],
                 a[0], a[1], a[2], a[3]);
    if constexpr (layer == 3) {  // next layer cinP=32: cols 32-63 must be zero
      const uint2 z = make_uint2(0u, 0u);
      *(uint2*)&U[XHo + kk * 72 + oc + 32] = z;
      *(uint2*)&U[XLo + kk * 72 + oc + 32] = z;
    }
    if constexpr (layer == 4) {  // next layer cinP=16: cols 16-31 must be zero
      const uint2 z = make_uint2(0u, 0u);
      *(uint2*)&U[XHo + kk * 72 + oc + 16] = z;
      *(uint2*)&U[XLo + kk * 72 + oc + 16] = z;
    }
  }
  __syncthreads();
}

// ======================= main kernel =======================
__global__ __launch_bounds__(NT, 8)
void scnn_main(const float* __restrict__ xin, const unsigned short* __restrict__ wsu,
               float* __restrict__ out) {
  __shared__ __align__(16) unsigned short U[NU];
  const int tid = threadIdx.x, b = blockIdx.x;
  const int lane = tid & 63, wv = tid >> 6;
  const int llo = lane & 31, lhi = lane >> 5;
  const int l15 = lane & 15, q4 = lane >> 4;
  const int lof = lane << 3;

  // ---- zero-fill entire X region (both planes contiguous: 6912 ush = 1728 uint2)
  for (int i = tid; i < 1728; i += NT)
    ((uint2*)&U[XHo])[i] = make_uint2(0u, 0u);
  __syncthreads();
  // ---- stage initial X: [k][c] stride 72, live cols 0..3, scale-folded
  for (int i = tid; i < 180; i += NT) {
    const int c = i / 45, k = i - c * 45;
    const float v = xin[(size_t)b * 180 + i] * scale_from_j(lidxf(k));
    const unsigned u = __float_as_uint(v);
    const unsigned short h = (unsigned short)(u >> 16);
    U[XHo + k * 72 + c] = h;
    U[XLo + k * 72 + c] = f2bf(v - bf2f(h));
  }
  __syncthreads();

  layer_body<0>(U, wsu, tid, wv, llo, lhi, l15, q4, lof);
  layer_body<1>(U, wsu, tid, wv, llo, lhi, l15, q4, lof);
  layer_body<2>(U, wsu, tid, wv, llo, lhi, l15, q4, lof);
  layer_body<3>(U, wsu, tid, wv, llo, lhi, l15, q4, lof);
  layer_body<4>(U, wsu, tid, wv, llo, lhi, l15, q4, lof);
  layer_body<5>(U, wsu, tid, wv, llo, lhi, l15, q4, lof);

  // ---- epilogue: out[b][c][k] = (XH+XL)[k][c] * (1/scale[k])
  for (int i = tid; i < 180; i += NT) {
    const int c = i / 45, k = i - c * 45;
    const float v = bf2f(U[XHo + k * 72 + c]) + bf2f(U[XLo + k * 72 + c]);
    out[(size_t)b * 180 + i] = v * rcp_from_j(lidxf(k));
  }
}

extern "C" void kernel_launch(void* const* d_in, const int* in_sizes, int n_in,
                              void* d_out, int out_size, void* d_ws, size_t ws_size,
                              hipStream_t stream) {
  (void)n_in; (void)out_size; (void)ws_size;
  const float* x    = (const float*)d_in[0];
  const float* sft  = (const float*)d_in[1];
  const float* isft = (const float*)d_in[2];
  const float* w1   = (const float*)d_in[3];
  const float* w2   = (const float*)d_in[4];
  const float* w3   = (const float*)d_in[5];
  const float* w4   = (const float*)d_in[6];
  const float* w5   = (const float*)d_in[7];
  const float* w6   = (const float*)d_in[8];
  float* out = (float*)d_out;
  unsigned short* wsu = (unsigned short*)d_ws;  // uses 151552 B of scratch
  const int nb = in_sizes[0] / 180;             // 50000
  scnn_prep<<<64, NT, 0, stream>>>(sft, isft, w1, w2, w3, w4, w5, w6, wsu);
  scnn_main<<<nb, NT, 0, stream>>>(x, wsu, out);
}

// Round 8
// 1014.617 us; speedup vs baseline: 1.4398x; 1.0001x over previous
//
#include <hip/hip_runtime.h>

#define NT 512

typedef __attribute__((ext_vector_type(8)))  short bh8;   // 8 bf16
typedef __attribute__((ext_vector_type(16))) float f16v;  // 32x32 acc
typedef __attribute__((ext_vector_type(4)))  float f4v;   // 16x16 acc

// ---- d_ws layout (ushort units): pre-swizzled 64-lane x 16B fragment dumps.
// Every frag is 512 ush (1KB); a wave loads it as base + lane*8 (fully coalesced).
#define FW_H    0      // sconv expanded-weight B-frags, 56 frags (28672)
#define FW_L    28672
#define W2A32_H 57344  // stage2 32x32 A-frags (isft), 9 frags (4608)
#define W2A32_L 61952
#define W3B_H   66560  // stage3 B-frags (scale*sft), 9 frags (4608)
#define W3B_L   71168  // end 75776 ush = 151552 B

// ---- LDS layout (ushort units) ----
// Activations y and s are stored in MFMA *consumer fragment layout* (frag =
// 512 ush, read as base + lane*8 -> conflict-free, immediate ds offsets):
//   y B-frags (32x32x16) [nt2][ks=0..2]: frag[lane*8+e] = y[o=nt2*32+(lane&31)]
//     [k = ks*16+(lane>>5)*8+e]   (max 6 frags = 3072 ush)
//   s A-frags (16x16x32) [mtO][sl=0..2]: frag[lane*8+e] = s[o=mtO*16+(lane&15)]
//     [p = sl*32+(lane>>4)*8+e]   (max 12 frags = 6144 ush)
// Same region (y dead before s written; barrier between). X planes stay
// [k][c] stride 72 with zero-padded OOB columns (r6 scheme).
#define SHo  0      // y/s frag region H plane (6144)
#define SLo  6144   // L plane
#define XHo  12288  // x planes [k][c] stride 72 (3456)
#define XLo  15744
#define NU   19200  // 38400 B -> 4 blocks/CU (512 thr: 32 waves/CU)

__device__ __forceinline__ unsigned short f2bf(float f) {  // RNE
  unsigned u = __float_as_uint(f);
  return (unsigned short)((u + 0x7fffu + ((u >> 16) & 1u)) >> 16);
}
__device__ __forceinline__ float bf2f(unsigned short h) {
  return __uint_as_float(((unsigned)h) << 16);
}
__device__ __forceinline__ int lidxf(int k) {  // degree band l/2 for coeff k
  return (k < 1) ? 0 : (k < 6) ? 1 : (k < 15) ? 2 : (k < 28) ? 3 : 4;
}
__device__ __forceinline__ float scale_from_j(int j) {  // sqrt(pi/(4j+1))
  float s = 1.7724539f;
  s = (j == 1) ? 0.79266548f : s;
  s = (j == 2) ? 0.59081795f : s;
  s = (j == 3) ? 0.49159026f : s;
  s = (j >= 4) ? 0.42988324f : s;
  return s;
}
__device__ __forceinline__ float rcp_from_j(int j) {  // 1/scale
  float s = 0.56418958f;
  s = (j == 1) ? 1.2615663f : s;
  s = (j == 2) ? 1.6925688f : s;
  s = (j == 3) ? 2.0342144f : s;
  s = (j >= 4) ? 2.3262120f : s;
  return s;
}
// packed split: hi = trunc-bf16 pair via v_perm; lo = trunc(v - bf2f(hi)) pair
__device__ __forceinline__ unsigned pk_hi(float a, float b) {
  return __builtin_amdgcn_perm(__float_as_uint(b), __float_as_uint(a), 0x07060302u);
}
__device__ __forceinline__ void split_store4(unsigned short* dh, unsigned short* dl,
                                             float v0, float v1, float v2, float v3) {
  const unsigned u0 = __float_as_uint(v0), u1 = __float_as_uint(v1);
  const unsigned u2 = __float_as_uint(v2), u3 = __float_as_uint(v3);
  const float d0 = v0 - __uint_as_float(u0 & 0xffff0000u);
  const float d1 = v1 - __uint_as_float(u1 & 0xffff0000u);
  const float d2 = v2 - __uint_as_float(u2 & 0xffff0000u);
  const float d3 = v3 - __uint_as_float(u3 & 0xffff0000u);
  *(uint2*)dh = make_uint2(pk_hi(v0, v1), pk_hi(v2, v3));
  *(uint2*)dl = make_uint2(pk_hi(d0, d1), pk_hi(d2, d3));
}

// ======================= pre-kernel: build fragment dumps =======================
__global__ void scnn_prep(const float* __restrict__ sft, const float* __restrict__ isft,
                          const float* __restrict__ w1, const float* __restrict__ w2,
                          const float* __restrict__ w3, const float* __restrict__ w4,
                          const float* __restrict__ w5, const float* __restrict__ w6,
                          unsigned short* __restrict__ wsu) {
  const int gid = blockIdx.x * NT + threadIdx.x;
  const int gstr = gridDim.x * NT;
  const float* wp[6] = {w1, w2, w3, w4, w5, w6};
  const int CIN[6] = {4, 16, 32, 64, 32, 16};
  const int COUT[6] = {16, 32, 64, 32, 16, 4};
  const int LG[6] = {3, 4, 5, 6, 5, 4};
  const int NST[6] = {2, 3, 5, 10, 5, 3};
  const int NTC[6] = {1, 2, 4, 2, 1, 1};
  const int FOFF[6] = {0, 2, 8, 28, 48, 53};
#pragma unroll
  for (int l = 0; l < 6; ++l) {
    const int cin = CIN[l], cout = COUT[l], lg = LG[l], cinP = 1 << lg;
    const int nst = NST[l];
    const int n = NTC[l] * nst * 512;
    const float* w = wp[l];
    const int base = FOFF[l] * 512;
    for (int i = gid; i < n; i += gstr) {
      const int fid = i >> 9, lane = (i >> 3) & 63, e = i & 7;
      const int nt = fid / nst, st = fid - nt * nst;
      const int o = nt * 16 + (lane & 15);
      const int s = st * 32 + (lane >> 4) * 8 + e;
      const int j = s >> lg, c = s & (cinP - 1);
      float v = 0.f;
      if (o < cout && j < 5 && c < cin) v = w[(o * cin + c) * 5 + j];
      const unsigned short h = f2bf(v);
      wsu[FW_H + base + i] = h;
      wsu[FW_L + base + i] = f2bf(v - bf2f(h));
    }
  }
  for (int i = gid; i < 9 * 512; i += gstr) {  // stage2 32x32 A-frags (isft)
    const int fid = i >> 9, lane = (i >> 3) & 63, e = i & 7;
    const int mt = fid / 3, ks = fid - mt * 3;
    const int p = mt * 32 + (lane & 31);
    const int k = ks * 16 + (lane >> 5) * 8 + e;
    const float v = (p < 90 && k < 45) ? isft[p * 45 + k] : 0.f;
    const unsigned short h = f2bf(v);
    wsu[W2A32_H + i] = h;
    wsu[W2A32_L + i] = f2bf(v - bf2f(h));
  }
  for (int i = gid; i < 9 * 512; i += gstr) {  // stage3 B-frags (scale*sft)
    const int fid = i >> 9, lane = (i >> 3) & 63, e = i & 7;
    const int ntK = fid / 3, sl = fid - ntK * 3;
    const int kk = ntK * 16 + (lane & 15);
    const int p = sl * 32 + (lane >> 4) * 8 + e;
    float v = 0.f;
    if (kk < 45 && p < 90) v = sft[kk * 90 + p] * scale_from_j(lidxf(kk));
    const unsigned short h = f2bf(v);
    wsu[W3B_H + i] = h;
    wsu[W3B_L + i] = f2bf(v - bf2f(h));
  }
}

// stage2 tile: C[m=p][n=o] += sum_k WI[p][k]*y[o][k], 32x32x16, K=48.
// y read from LDS B-frags: base + lane*8, ks via immediate offsets.
__device__ __forceinline__ f16v s2tile(const unsigned short* U,
                                       const unsigned short* __restrict__ wsu,
                                       int mt, int nt, int lof) {
  f16v a;
#pragma unroll
  for (int e = 0; e < 16; ++e) a[e] = 0.f;
  const unsigned short* fh = wsu + W2A32_H + mt * 3 * 512 + lof;
  const unsigned short* yb = U + SHo + nt * 3 * 512 + lof;
#pragma unroll
  for (int ks = 0; ks < 3; ++ks) {
    const bh8 ah = *(const bh8*)&fh[ks * 512];
    const bh8 al = *(const bh8*)&fh[(W2A32_L - W2A32_H) + ks * 512];
    const bh8 bhv = *(const bh8*)&yb[ks * 512];
    const bh8 blv = *(const bh8*)&yb[(SLo - SHo) + ks * 512];
    a = __builtin_amdgcn_mfma_f32_32x32x16_bf16(ah, bhv, a, 0, 0, 0);
    a = __builtin_amdgcn_mfma_f32_32x32x16_bf16(al, bhv, a, 0, 0, 0);
    a = __builtin_amdgcn_mfma_f32_32x32x16_bf16(ah, blv, a, 0, 0, 0);
  }
  return a;
}
// write s (ReLU'd) into stage-(d) A-frag layout.
// lane (llo,lhi) holds s[o=nt*32+llo][p=mt*32+g*8+lhi*4+r]; frag (mtO=o>>4, sl=mt),
// idx = (g*16+(o&15))*8 + lhi*4 + r.
__device__ __forceinline__ void writes_s(unsigned short* U, f16v acc, int mt,
                                         int nt, int llo, int lhi) {
  const int so = ((nt * 2 + (llo >> 4)) * 3 + mt) * 512 + (llo & 15) * 8 + lhi * 4;
#pragma unroll
  for (int g = 0; g < 4; ++g) {
    const int off = so + g * 128;
    split_store4(&U[SHo + off], &U[SLo + off],
                 fmaxf(acc[g * 4 + 0], 0.f), fmaxf(acc[g * 4 + 1], 0.f),
                 fmaxf(acc[g * 4 + 2], 0.f), fmaxf(acc[g * 4 + 3], 0.f));
  }
}

// ---- stage (a) tile, mt compile-time: constant st-window -> full unroll.
// OOB columns clamp to col 64 (always-zero pad). Output y written into
// stage-(b) B-frag layout.
template <int layer, int mt>
__device__ __forceinline__ void atile(unsigned short* U,
                                      const unsigned short* __restrict__ wsu,
                                      int nt, int l15, int q4, int lof) {
  constexpr int lg   = (layer == 0) ? 3 : (layer == 1) ? 4 : (layer == 2) ? 5
                     : (layer == 3) ? 6 : (layer == 4) ? 5 : 4;
  constexpr int cinP = 1 << lg;
  constexpr int NSTc = (layer == 0) ? 2 : (layer == 1) ? 3 : (layer == 2) ? 5
                     : (layer == 3) ? 10 : (layer == 4) ? 5 : 3;
  constexpr int FOFFc= (layer == 0) ? 0 : (layer == 1) ? 2 : (layer == 2) ? 8
                     : (layer == 3) ? 28 : (layer == 4) ? 48 : 53;
  constexpr int hi5 = (5 * cinP + 31) >> 5;
  constexpr int hi4 = (4 * cinP + 31) >> 5;
  constexpr int lo3 = (3 * cinP) >> 5;
  constexpr int lo4 = cinP >> 3;
  constexpr int lo = (mt == 0) ? 0 : (mt == 1) ? lo3 : lo4;
  constexpr int hi = (mt == 0) ? hi4 : hi5;
  (void)cinP;

  const int k = mt * 16 + l15;
  const int jb = lidxf(k) << lg;
  const unsigned short* wfh = wsu + FW_H + (FOFFc + nt * NSTc) * 512 + lof;
  f4v a;
  a[0] = a[1] = a[2] = a[3] = 0.f;
#pragma unroll
  for (int st = lo; st < hi; ++st) {
    const int S = st * 32 + q4 * 8;
    const unsigned c0 = (unsigned)(S - jb);
    const unsigned cc = c0 < 64u ? c0 : 64u;  // v_min_u32: OOB -> zero pad col
    const unsigned short* xp = &U[XHo + k * 72 + (int)cc];
    const bh8 xh = *(const bh8*)xp;
    const bh8 xl = *(const bh8*)(xp + (XLo - XHo));  // folds to ds_read offset
    const bh8 wh = *(const bh8*)&wfh[st * 512];
    const bh8 wl = *(const bh8*)&wfh[(FW_L - FW_H) + st * 512];
    a = __builtin_amdgcn_mfma_f32_16x16x32_bf16(xh, wh, a, 0, 0, 0);
    a = __builtin_amdgcn_mfma_f32_16x16x32_bf16(xl, wh, a, 0, 0, 0);
    a = __builtin_amdgcn_mfma_f32_16x16x32_bf16(xh, wl, a, 0, 0, 0);
  }
  // lane holds y[o=nt*16+l15][k=mt*16+q4*4+j] -> stage-(b) B-frag:
  // frag (nt2=nt>>1, ks=mt), idx = ((q4>>1)*32+(nt&1)*16+l15)*8 + (q4&1)*4 + j
  const int off = (((nt >> 1) * 3 + mt) << 9) +
                  ((q4 >> 1) * 32 + (nt & 1) * 16 + l15) * 8 + (q4 & 1) * 4;
  split_store4(&U[SHo + off], &U[SLo + off], a[0], a[1], a[2], a[3]);
}

// ======================= per-layer body (compile-time specialized) =======
// 8 waves per element: tile loops stride by 8 (round-3 wide distribution).
template <int layer>
__device__ __forceinline__ void layer_body(unsigned short* U,
                                           const unsigned short* __restrict__ wsu,
                                           int tid, int wv, int llo, int lhi,
                                           int l15, int q4, int lof) {
  constexpr int nt16 = (layer == 2) ? 4 : (layer == 1 || layer == 3) ? 2 : 1;
  constexpr int n32  = (layer == 2) ? 2 : 1;

  // ---- (a) sconv via MFMA, pre-swizzled weight frags -> y B-frags
  {
    constexpr int T = 3 * nt16;
    for (int t = wv; t < T; t += 8) {
      const int mt = t % 3, nt = t / 3;
      if (mt == 0)      atile<layer, 0>(U, wsu, nt, l15, q4, lof);
      else if (mt == 1) atile<layer, 1>(U, wsu, nt, l15, q4, lof);
      else              atile<layer, 2>(U, wsu, nt, l15, q4, lof);
    }
  }
  __syncthreads();

  // ---- (b)+(c) stage2 MFMA, acc in regs across barrier; s -> A-frags
  {
    constexpr int T2 = 3 * n32;  // <= 6 < 8 waves: one tile per wave
    const bool hA = wv < T2;
    f16v a0;
    if (hA) a0 = s2tile(U, wsu, wv % 3, wv / 3, lof);
    __syncthreads();
    if (hA) writes_s(U, a0, wv % 3, wv / 3, llo, lhi);
  }
  __syncthreads();

  // ---- (d) stage3 MFMA: A = s frags (LDS, linear), B = WS' frags (global).
  //      C[m=o][n=k']: lane k' fixed, o consecutive -> vector X[k'][o] writes.
  //      L3/L4 additionally re-zero the stale cols visible to the next layer.
  constexpr int T3 = 3 * nt16;
  for (int t = wv; t < T3; t += 8) {
    const int ntK = t % 3, mtO = t / 3;
    const unsigned short* fb = wsu + W3B_H + ntK * 3 * 512 + lof;
    const unsigned short* ab = U + SHo + mtO * 3 * 512 + lof;
    f4v a;
    a[0] = a[1] = a[2] = a[3] = 0.f;
#pragma unroll
    for (int sl = 0; sl < 3; ++sl) {
      const bh8 ah = *(const bh8*)&ab[sl * 512];
      const bh8 al = *(const bh8*)&ab[(SLo - SHo) + sl * 512];
      const bh8 bhv = *(const bh8*)&fb[sl * 512];
      const bh8 blv = *(const bh8*)&fb[(W3B_L - W3B_H) + sl * 512];
      a = __builtin_amdgcn_mfma_f32_16x16x32_bf16(ah, bhv, a, 0, 0, 0);
      a = __builtin_amdgcn_mfma_f32_16x16x32_bf16(al, bhv, a, 0, 0, 0);
      a = __builtin_amdgcn_mfma_f32_16x16x32_bf16(ah, blv, a, 0, 0, 0);
    }
    const int kk = ntK * 16 + l15;     // k' row (fixed per lane)
    const int oc = mtO * 16 + q4 * 4;  // o columns (consecutive)
    split_store4(&U[XHo + kk * 72 + oc], &U[XLo + kk * 72 + oc],
                 a[0], a[1], a[2], a[3]);
    if constexpr (layer == 3) {  // next layer cinP=32: cols 32-63 must be zero
      const uint2 z = make_uint2(0u, 0u);
      *(uint2*)&U[XHo + kk * 72 + oc + 32] = z;
      *(uint2*)&U[XLo + kk * 72 + oc + 32] = z;
    }
    if constexpr (layer == 4) {  // next layer cinP=16: cols 16-31 must be zero
      const uint2 z = make_uint2(0u, 0u);
      *(uint2*)&U[XHo + kk * 72 + oc + 16] = z;
      *(uint2*)&U[XLo + kk * 72 + oc + 16] = z;
    }
  }
  __syncthreads();
}

// ======================= main kernel =======================
__global__ __launch_bounds__(NT, 8)
void scnn_main(const float* __restrict__ xin, const unsigned short* __restrict__ wsu,
               float* __restrict__ out) {
  __shared__ __align__(16) unsigned short U[NU];
  const int tid = threadIdx.x, b = blockIdx.x;
  const int lane = tid & 63, wv = tid >> 6;
  const int llo = lane & 31, lhi = lane >> 5;
  const int l15 = lane & 15, q4 = lane >> 4;
  const int lof = lane << 3;

  // ---- zero-fill entire X region (both planes contiguous: 6912 ush = 1728 uint2)
  for (int i = tid; i < 1728; i += NT)
    ((uint2*)&U[XHo])[i] = make_uint2(0u, 0u);
  __syncthreads();
  // ---- stage initial X: [k][c] stride 72, live cols 0..3, scale-folded
  for (int i = tid; i < 180; i += NT) {
    const int c = i / 45, k = i - c * 45;
    const float v = xin[(size_t)b * 180 + i] * scale_from_j(lidxf(k));
    const unsigned u = __float_as_uint(v);
    const unsigned short h = (unsigned short)(u >> 16);
    U[XHo + k * 72 + c] = h;
    U[XLo + k * 72 + c] = f2bf(v - bf2f(h));
  }
  __syncthreads();

  layer_body<0>(U, wsu, tid, wv, llo, lhi, l15, q4, lof);
  layer_body<1>(U, wsu, tid, wv, llo, lhi, l15, q4, lof);
  layer_body<2>(U, wsu, tid, wv, llo, lhi, l15, q4, lof);
  layer_body<3>(U, wsu, tid, wv, llo, lhi, l15, q4, lof);
  layer_body<4>(U, wsu, tid, wv, llo, lhi, l15, q4, lof);
  layer_body<5>(U, wsu, tid, wv, llo, lhi, l15, q4, lof);

  // ---- epilogue: out[b][c][k] = (XH+XL)[k][c] * (1/scale[k])
  for (int i = tid; i < 180; i += NT) {
    const int c = i / 45, k = i - c * 45;
    const float v = bf2f(U[XHo + k * 72 + c]) + bf2f(U[XLo + k * 72 + c]);
    out[(size_t)b * 180 + i] = v * rcp_from_j(lidxf(k));
  }
}

extern "C" void kernel_launch(void* const* d_in, const int* in_sizes, int n_in,
                              void* d_out, int out_size, void* d_ws, size_t ws_size,
                              hipStream_t stream) {
  (void)n_in; (void)out_size; (void)ws_size;
  const float* x    = (const float*)d_in[0];
  const float* sft  = (const float*)d_in[1];
  const float* isft = (const float*)d_in[2];
  const float* w1   = (const float*)d_in[3];
  const float* w2   = (const float*)d_in[4];
  const float* w3   = (const float*)d_in[5];
  const float* w4   = (const float*)d_in[6];
  const float* w5   = (const float*)d_in[7];
  const float* w6   = (const float*)d_in[8];
  float* out = (float*)d_out;
  unsigned short* wsu = (unsigned short*)d_ws;  // uses 151552 B of scratch
  const int nb = in_sizes[0] / 180;             // 50000
  scnn_prep<<<64, NT, 0, stream>>>(sft, isft, w1, w2, w3, w4, w5, w6, wsu);
  scnn_main<<<nb, NT, 0, stream>>>(x, wsu, out);
}